// Round 1
// baseline (2945.491 us; speedup 1.0000x reference)
//
#include <hip/hip_runtime.h>
#include <hip/hip_bf16.h>

// ---------------- constants ----------------
#define NB   4
#define DIM  128
#define KC   64
#define HH   48
#define WW   900
#define WPAD 1100
#define NT   30
#define OC1  256
#define OC2  512
#define OC3  1024

typedef __attribute__((ext_vector_type(8))) short bf16x8;
typedef __attribute__((ext_vector_type(4))) float f32x4;
typedef unsigned short u16;

__device__ __forceinline__ u16 f2bf(float f){
  __hip_bfloat16 h = __float2bfloat16(f);
  u16 u; __builtin_memcpy(&u, &h, 2); return u;
}
__device__ __forceinline__ float bf2f(u16 u){
  __hip_bfloat16 h; __builtin_memcpy(&h, &u, 2); return __bfloat162float(h);
}

// ---------------- VLAD branch (fp32) ----------------

// x [n][c][h][w] -> xt [n][w][c*48+h]   (2D transpose 6144x900 per n)
__global__ __launch_bounds__(256) void transpose_xt(const float* __restrict__ x, float* __restrict__ xt){
  __shared__ float tile[32][33];
  int n = blockIdx.z;
  int r0 = blockIdx.y*32, w0 = blockIdx.x*32;
  int t = threadIdx.x;
  int tr = t >> 5, tc = t & 31;
  #pragma unroll
  for (int i = 0; i < 4; ++i){
    int r = r0 + tr + i*8, w = w0 + tc;
    tile[tr + i*8][tc] = (w < WW) ? x[((size_t)n*(DIM*HH) + r)*WW + w] : 0.f;
  }
  __syncthreads();
  #pragma unroll
  for (int i = 0; i < 4; ++i){
    int w = w0 + tr + i*8, r = r0 + tc;
    if (w < WW) xt[((size_t)n*WW + w)*(DIM*HH) + r] = tile[tc][tr + i*8];
  }
}

// logits = einsum('nchw,kc') + b ; softmax over k ; store a [n][h][w][k]
__global__ __launch_bounds__(256) void vlad_softmax(const float* __restrict__ x,
    const float* __restrict__ conv_w, const float* __restrict__ conv_b, float* __restrict__ a){
  __shared__ float cwT[DIM*KC];   // [c][k]
  __shared__ float cbs[KC];
  int t = threadIdx.x;
  for (int i = t; i < DIM*KC; i += 256){ int c = i >> 6, k = i & 63; cwT[i] = conv_w[k*DIM + c]; }
  if (t < KC) cbs[t] = conv_b[t];
  __syncthreads();
  int w = blockIdx.x*256 + t, h = blockIdx.y, n = blockIdx.z;
  bool ok = (w < WW);
  float lg[KC];
  #pragma unroll
  for (int k = 0; k < KC; ++k) lg[k] = cbs[k];
  const float* xp = x + (size_t)n*DIM*HH*WW + (size_t)h*WW + (ok ? w : 0);
  for (int c = 0; c < DIM; ++c){
    float xv = ok ? xp[(size_t)c*HH*WW] : 0.f;
    const float* cw = &cwT[c*KC];
    #pragma unroll
    for (int k = 0; k < KC; ++k) lg[k] += xv * cw[k];
  }
  float m = lg[0];
  #pragma unroll
  for (int k = 1; k < KC; ++k) m = fmaxf(m, lg[k]);
  float s = 0.f;
  #pragma unroll
  for (int k = 0; k < KC; ++k){ lg[k] = __expf(lg[k]-m); s += lg[k]; }
  float inv = 1.f/s;
  if (ok){
    float* dst = a + (((size_t)(n*HH + h))*WW + w)*KC;
    #pragma unroll
    for (int k = 0; k < KC; k += 4){
      float4 v = make_float4(lg[k]*inv, lg[k+1]*inv, lg[k+2]*inv, lg[k+3]*inv);
      *(float4*)&dst[k] = v;
    }
  }
}

// per (n,w): xa[k][c] = sum_h a[k,h]*x[c,h] ; a_sum[k] = sum_h a[k,h]
__global__ __launch_bounds__(256) void vlad_xa(const float* __restrict__ xt, const float* __restrict__ a,
    float* __restrict__ xa, float* __restrict__ a_sum){
  __shared__ float aT[HH][KC];     // [h][k]
  __shared__ float xT[DIM*HH];     // [c][h]
  int t = threadIdx.x, w = blockIdx.x, n = blockIdx.y;
  for (int i = t; i < HH*KC; i += 256){
    int h = i >> 6, k = i & 63;
    aT[h][k] = a[(((size_t)(n*HH + h))*WW + w)*KC + k];
  }
  {
    const float4* src = (const float4*)(xt + ((size_t)n*WW + w)*(DIM*HH));
    float4* dst4 = (float4*)xT;
    for (int i = t; i < (DIM*HH)/4; i += 256) dst4[i] = src[i];
  }
  __syncthreads();
  int k = t >> 2, cb4 = t & 3;
  float areg[HH];
  #pragma unroll
  for (int h = 0; h < HH; ++h) areg[h] = aT[h][k];
  float* dst = xa + (((size_t)n*WW + w)*KC + k)*DIM;
  #pragma unroll 2
  for (int j = 0; j < 32; ++j){
    const float4* xr = (const float4*)&xT[(cb4 + 4*j)*HH];
    float s = 0.f;
    #pragma unroll
    for (int h4 = 0; h4 < HH/4; ++h4){
      float4 xv = xr[h4];
      s += areg[h4*4+0]*xv.x + areg[h4*4+1]*xv.y + areg[h4*4+2]*xv.z + areg[h4*4+3]*xv.w;
    }
    dst[cb4 + 4*j] = s;
  }
  if (t < KC){
    float s = 0.f;
    #pragma unroll
    for (int h = 0; h < HH; ++h) s += aT[h][t];
    a_sum[((size_t)n*WW + w)*KC + t] = s;
  }
}

// window sums + centers subtraction + intra (per-cluster) L2 norm
__global__ __launch_bounds__(128) void vlad_win(const float* __restrict__ xa, const float* __restrict__ a_sum,
    const float* __restrict__ centers, float* __restrict__ vlad){
  int c = threadIdx.x, k = blockIdx.x, tt = blockIdx.y, n = blockIdx.z;
  float acc = 0.f, S = 0.f;
  for (int p = 0; p < 200; ++p){
    int w = (30*tt + p + 800) % 900;
    acc += xa[(((size_t)n*WW + w)*KC + k)*DIM + c];
    S   += a_sum[((size_t)n*WW + w)*KC + k];
  }
  float v = acc - centers[k*DIM + c]*S;
  float ss = v*v;
  #pragma unroll
  for (int m = 1; m < 64; m <<= 1) ss += __shfl_xor(ss, m);
  __shared__ float red[2];
  if ((c & 63) == 0) red[c >> 6] = ss;
  __syncthreads();
  float tot = red[0] + red[1];
  float inv = 1.f / fmaxf(sqrtf(tot), 1e-12f);
  vlad[(((size_t)(n*NT + tt))*KC + k)*DIM + c] = v*inv;
}

// global L2 over the 8192-dim vlad row, in place
__global__ __launch_bounds__(256) void vlad_gnorm(float* __restrict__ vlad){
  int row = blockIdx.x, t = threadIdx.x;
  float4* v = (float4*)(vlad + (size_t)row*(KC*DIM));
  float4 r[8]; float ss = 0.f;
  #pragma unroll
  for (int i = 0; i < 8; ++i){
    r[i] = v[t + i*256];
    ss += r[i].x*r[i].x + r[i].y*r[i].y + r[i].z*r[i].z + r[i].w*r[i].w;
  }
  #pragma unroll
  for (int m = 1; m < 64; m <<= 1) ss += __shfl_xor(ss, m);
  __shared__ float red[4];
  if ((t & 63) == 0) red[t >> 6] = ss;
  __syncthreads();
  float tot = red[0]+red[1]+red[2]+red[3];
  float inv = 1.f / fmaxf(sqrtf(tot), 1e-12f);
  #pragma unroll
  for (int i = 0; i < 8; ++i){
    float4 o = r[i]; o.x*=inv; o.y*=inv; o.z*=inv; o.w*=inv;
    v[t + i*256] = o;
  }
}

// ---------------- conv tower (bf16 MFMA, NHWC) ----------------

// x [n][c][h][w] --circular-pad--> xpb [n][h][w'=1100][c] bf16
__global__ __launch_bounds__(256) void build_xpb(const float* __restrict__ x, u16* __restrict__ xpb){
  __shared__ u16 tile[DIM][33];
  int t = threadIdx.x, h = blockIdx.y, n = blockIdx.z;
  int w0 = blockIdx.x*32;
  #pragma unroll
  for (int i = 0; i < 16; ++i){
    int e = t + i*256;
    int c = e >> 5, wl = e & 31;
    int wq = w0 + wl;
    float v = 0.f;
    if (wq < WPAD){
      int wsrc = (wq + 800) % 900;
      v = x[((size_t)(n*DIM + c)*HH + h)*WW + wsrc];
    }
    tile[c][wl] = f2bf(v);
  }
  __syncthreads();
  #pragma unroll
  for (int i = 0; i < 16; ++i){
    int e = t + i*256;
    int wl = e >> 7, c = e & 127;
    int wq = w0 + wl;
    if (wq < WPAD) xpb[((size_t)(n*HH + h)*WPAD + wq)*DIM + c] = tile[c][wl];
  }
}

// w OIHW fp32 -> wp [tap=dh*5+dw][oc][ic] bf16
__global__ __launch_bounds__(256) void pack_w(const float* __restrict__ w, u16* __restrict__ wp, int OC, int IC){
  int idx = blockIdx.x*256 + threadIdx.x;
  int total = OC*IC*25;
  if (idx >= total) return;
  int ic = idx % IC; int r = idx / IC; int oc = r % OC; int tap = r / OC;
  wp[idx] = f2bf(w[((size_t)oc*IC + ic)*25 + tap]);
}

// 5x5 conv, pad 2, NHWC bf16 in/out, fp32 bias. Tile: 64oc x 64w per block, one (n,h).
template<int IC, int OC, int H>
__global__ __launch_bounds__(256) void conv5x5(const u16* __restrict__ in, const u16* __restrict__ wp,
    const float* __restrict__ bias, u16* __restrict__ out){
  constexpr int NICB = IC/128;
  __shared__ u16 sIn[68][136];   // [w'][ic] padded to 136 (272B = 17x16B)
  __shared__ u16 sW[64][136];    // [oc][ic]
  int t = threadIdx.x;
  int w0  = blockIdx.x * 64;
  int ocb = blockIdx.y * 64;
  int nh = blockIdx.z; int n = nh / H, h = nh % H;
  int wave = t >> 6, lane = t & 63;
  int ocw = (wave & 1)*32, wvw = (wave >> 1)*32;
  int lr = lane & 15, lgp = lane >> 4;
  f32x4 acc[2][2] = {};
  for (int dh = 0; dh < 5; ++dh){
    int hin = h + dh - 2;
    if (hin < 0 || hin >= H) continue;
    const u16* inrow = in + (size_t)(n*H + hin)*WPAD*IC;
    for (int icb = 0; icb < NICB; ++icb){
      __syncthreads();
      for (int v = t; v < 68*16; v += 256){
        int wl = v >> 4, icv = v & 15;
        int wg = w0 - 2 + wl;
        uint4 val = make_uint4(0,0,0,0);
        if (wg >= 0 && wg < WPAD) val = *(const uint4*)(inrow + (size_t)wg*IC + icb*128 + icv*8);
        *(uint4*)&sIn[wl][icv*8] = val;
      }
      for (int dw = 0; dw < 5; ++dw){
        __syncthreads();
        {
          int tap = dh*5 + dw;
          const u16* wsrc = wp + ((size_t)tap*OC + ocb)*IC + icb*128;
          #pragma unroll
          for (int v0 = 0; v0 < 4; ++v0){
            int v = t + v0*256;
            int ol = v >> 4, icv = v & 15;
            *(uint4*)&sW[ol][icv*8] = *(const uint4*)(wsrc + (size_t)ol*IC + icv*8);
          }
        }
        __syncthreads();
        #pragma unroll
        for (int k0 = 0; k0 < 128; k0 += 32){
          bf16x8 a0 = *(const bf16x8*)&sW[ocw + lr     ][k0 + lgp*8];
          bf16x8 a1 = *(const bf16x8*)&sW[ocw + 16 + lr][k0 + lgp*8];
          bf16x8 b0 = *(const bf16x8*)&sIn[wvw + lr      + dw][k0 + lgp*8];
          bf16x8 b1 = *(const bf16x8*)&sIn[wvw + 16 + lr + dw][k0 + lgp*8];
          acc[0][0] = __builtin_amdgcn_mfma_f32_16x16x32_bf16(a0, b0, acc[0][0], 0, 0, 0);
          acc[0][1] = __builtin_amdgcn_mfma_f32_16x16x32_bf16(a0, b1, acc[0][1], 0, 0, 0);
          acc[1][0] = __builtin_amdgcn_mfma_f32_16x16x32_bf16(a1, b0, acc[1][0], 0, 0, 0);
          acc[1][1] = __builtin_amdgcn_mfma_f32_16x16x32_bf16(a1, b1, acc[1][1], 0, 0, 0);
        }
      }
    }
  }
  const size_t obase = (size_t)(n*H + h)*WPAD*OC;
  #pragma unroll
  for (int jj = 0; jj < 2; ++jj){
    int oc = ocb + ocw + jj*16 + lgp*4;
    float4 bv = *(const float4*)&bias[oc];
    #pragma unroll
    for (int j = 0; j < 2; ++j){
      int wg = w0 + wvw + j*16 + lr;
      if (wg < WPAD){
        f32x4 av = acc[jj][j];
        ushort4 o;
        o.x = f2bf(av[0] + bv.x);
        o.y = f2bf(av[1] + bv.y);
        o.z = f2bf(av[2] + bv.z);
        o.w = f2bf(av[3] + bv.w);
        *(ushort4*)(out + obase + (size_t)wg*OC + oc) = o;
      }
    }
  }
}

// leaky(0.2) + maxpool 3x3 stride(3,1) wpad 1   (leaky after max: monotonic)
__global__ __launch_bounds__(256) void pool1k(const u16* __restrict__ in, u16* __restrict__ out){
  int oc = threadIdx.x, wo = blockIdx.x, ho = blockIdx.y, n = blockIdx.z;
  float m = -1e30f;
  #pragma unroll
  for (int kh = 0; kh < 3; ++kh){
    const u16* row = in + (size_t)(n*HH + ho*3 + kh)*WPAD*OC1;
    #pragma unroll
    for (int kw = 0; kw < 3; ++kw){
      int wi = wo - 1 + kw;
      if (wi >= 0 && wi < WPAD) m = fmaxf(m, bf2f(row[(size_t)wi*OC1 + oc]));
    }
  }
  m = (m > 0.f) ? m : 0.2f*m;
  out[((size_t)(n*16 + ho)*WPAD + wo)*OC1 + oc] = f2bf(m);
}

// leaky(0.2) + maxpool 4x5 stride(4,1) wpad 2
__global__ __launch_bounds__(256) void pool2k(const u16* __restrict__ in, u16* __restrict__ out){
  int wo = blockIdx.x, ho = blockIdx.y, n = blockIdx.z;
  #pragma unroll
  for (int j = 0; j < 2; ++j){
    int oc = threadIdx.x + j*256;
    float m = -1e30f;
    #pragma unroll
    for (int kh = 0; kh < 4; ++kh){
      const u16* row = in + (size_t)(n*16 + ho*4 + kh)*WPAD*OC2;
      #pragma unroll
      for (int kw = 0; kw < 5; ++kw){
        int wi = wo - 2 + kw;
        if (wi >= 0 && wi < WPAD) m = fmaxf(m, bf2f(row[(size_t)wi*OC2 + oc]));
      }
    }
    m = (m > 0.f) ? m : 0.2f*m;
    out[((size_t)(n*4 + ho)*WPAD + wo)*OC2 + oc] = f2bf(m);
  }
}

// maxpool 4x200, sample every 30 -> xfraw [n][t][1024] fp32  (no activation)
__global__ __launch_bounds__(256) void pool3k(const u16* __restrict__ in, float* __restrict__ xfraw){
  int tt = blockIdx.x, ocg = blockIdx.y, n = blockIdx.z;
  int oc = ocg*256 + threadIdx.x;
  float m = -1e30f;
  for (int hh = 0; hh < 4; ++hh){
    const u16* row = in + (size_t)(n*4 + hh)*WPAD*OC3 + (size_t)(30*tt)*OC3 + oc;
    for (int p = 0; p < 200; ++p) m = fmaxf(m, bf2f(row[(size_t)p*OC3]));
  }
  xfraw[(size_t)(n*NT + tt)*OC3 + oc] = m;
}

__global__ __launch_bounds__(256) void xf_norm(const float* __restrict__ xfraw, float* __restrict__ xf){
  int row = blockIdx.x, t = threadIdx.x;
  const float* src = xfraw + (size_t)row*OC3;
  float v[4]; float ss = 0.f;
  #pragma unroll
  for (int j = 0; j < 4; ++j){ v[j] = src[t + j*256]; ss += v[j]*v[j]; }
  #pragma unroll
  for (int m = 1; m < 64; m <<= 1) ss += __shfl_xor(ss, m);
  __shared__ float red[4];
  if ((t & 63) == 0) red[t >> 6] = ss;
  __syncthreads();
  float tot = red[0]+red[1]+red[2]+red[3];
  float inv = 1.f/fmaxf(sqrtf(tot), 1e-12f);
  float* dst = xf + (size_t)row*OC3;
  #pragma unroll
  for (int j = 0; j < 4; ++j) dst[t + j*256] = v[j]*inv;
}

// out_row = l2n( [vlad_row(8192), xf_row(1024)] @ W.T + b )
__global__ __launch_bounds__(256) void final_mlp(const float* __restrict__ vlad, const float* __restrict__ xf,
    const float* __restrict__ W, const float* __restrict__ b, float* __restrict__ out){
  __shared__ float feat[9216];
  __shared__ float red[4];
  int row = blockIdx.x, t = threadIdx.x;
  {
    const float4* v = (const float4*)(vlad + (size_t)row*8192);
    float4* f4 = (float4*)feat;
    for (int i = t; i < 2048; i += 256) f4[i] = v[i];
    const float4* xv = (const float4*)(xf + (size_t)row*1024);
    if (t < 256) f4[2048 + t] = xv[t];
  }
  __syncthreads();
  const float* wr = W + (size_t)t*9216;
  float acc = b[t];
  for (int i = 0; i < 9216; i += 4){
    float4 wv = *(const float4*)&wr[i];
    acc += feat[i]*wv.x + feat[i+1]*wv.y + feat[i+2]*wv.z + feat[i+3]*wv.w;
  }
  float ss = acc*acc;
  #pragma unroll
  for (int m = 1; m < 64; m <<= 1) ss += __shfl_xor(ss, m);
  if ((t & 63) == 0) red[t >> 6] = ss;
  __syncthreads();
  float tot = red[0]+red[1]+red[2]+red[3];
  float inv = 1.f/fmaxf(sqrtf(tot), 1e-12f);
  out[(size_t)row*256 + t] = acc*inv;
}

// ---------------- launch ----------------
extern "C" void kernel_launch(void* const* d_in, const int* in_sizes, int n_in,
                              void* d_out, int out_size, void* d_ws, size_t ws_size,
                              hipStream_t stream){
  const float* x       = (const float*)d_in[0];
  const float* centers = (const float*)d_in[1];
  const float* conv_w  = (const float*)d_in[2];
  const float* conv_b  = (const float*)d_in[3];
  const float* w1      = (const float*)d_in[4];
  const float* b1      = (const float*)d_in[5];
  const float* w2      = (const float*)d_in[6];
  const float* b2      = (const float*)d_in[7];
  const float* w3      = (const float*)d_in[8];
  const float* b3      = (const float*)d_in[9];
  const float* mlp_w   = (const float*)d_in[10];
  const float* mlp_b   = (const float*)d_in[11];
  float* out = (float*)d_out;
  char* ws = (char*)d_ws;
  const size_t MB = 1ull << 20;
  if (ws_size < 248*MB) return;  // need ~247.5 MiB with phase-overlapped arena

  // persistent small buffers
  float* vlad  = (float*)(ws + 0);        // 3.75 MiB
  float* xf    = (float*)(ws + 4*MB);     // 0.47 MiB
  float* asum  = (float*)(ws + 5*MB);     // 0.88 MiB
  float* xfraw = (float*)(ws + 6*MB);     // 0.47 MiB
  char*  AR    = ws + 7*MB;               // arena (241 MiB), phase-reused
  // VLAD phase
  float* xt = (float*)(AR + 0);           // 84.4 MiB
  float* a  = (float*)(AR + 85*MB);       // 42.2 MiB
  float* xa = (float*)(AR + 128*MB);      // 112.5 MiB
  // conv phase (starts after vlad_win; regions recycled)
  u16* xpb = (u16*)(AR + 0);              // 51.6 MiB (over xt)
  u16* h1  = (u16*)(AR + 52*MB);          // 103.1 MiB (over a/xa)
  u16* p1  = (u16*)(AR + 156*MB);         // 34.4 MiB
  u16* wp1 = (u16*)(AR + 191*MB);         // 1.6 MiB
  u16* wp2 = (u16*)(AR + 193*MB);         // 6.25 MiB
  u16* wp3 = (u16*)(AR + 200*MB);         // 25 MiB
  u16* h2  = (u16*)(AR + 52*MB);          // 68.75 MiB (over h1)
  u16* p2  = (u16*)(AR + 122*MB);         // 17.2 MiB
  u16* h3  = (u16*)(AR + 0);              // 34.4 MiB (over xpb)

  // ---- VLAD (fp32) ----
  transpose_xt<<<dim3(29,192,NB), 256, 0, stream>>>(x, xt);
  vlad_softmax<<<dim3(4,HH,NB), 256, 0, stream>>>(x, conv_w, conv_b, a);
  vlad_xa<<<dim3(WW,NB), 256, 0, stream>>>(xt, a, xa, asum);
  vlad_win<<<dim3(KC,NT,NB), 128, 0, stream>>>(xa, asum, centers, vlad);
  vlad_gnorm<<<dim3(NB*NT), 256, 0, stream>>>(vlad);

  // ---- conv tower (bf16 MFMA) ----
  pack_w<<<dim3(3200),  256, 0, stream>>>(w1, wp1, OC1, DIM);
  pack_w<<<dim3(12800), 256, 0, stream>>>(w2, wp2, OC2, OC1);
  pack_w<<<dim3(51200), 256, 0, stream>>>(w3, wp3, OC3, OC2);
  build_xpb<<<dim3(35,HH,NB), 256, 0, stream>>>(x, xpb);
  conv5x5<128,256,48><<<dim3(18, OC1/64, NB*HH), 256, 0, stream>>>(xpb, wp1, b1, h1);
  pool1k<<<dim3(WPAD,16,NB), 256, 0, stream>>>(h1, p1);
  conv5x5<256,512,16><<<dim3(18, OC2/64, NB*16), 256, 0, stream>>>(p1, wp2, b2, h2);
  pool2k<<<dim3(WPAD,4,NB), 256, 0, stream>>>(h2, p2);
  conv5x5<512,1024,4><<<dim3(18, OC3/64, NB*4), 256, 0, stream>>>(p2, wp3, b3, h3);
  pool3k<<<dim3(NT,4,NB), 256, 0, stream>>>(h3, xfraw);
  xf_norm<<<dim3(NB*NT), 256, 0, stream>>>(xfraw, xf);

  // ---- head ----
  final_mlp<<<dim3(NB*NT), 256, 0, stream>>>(vlad, xf, mlp_w, mlp_b, out);
}

// Round 2
// 2427.955 us; speedup vs baseline: 1.2132x; 1.2132x over previous
//
#include <hip/hip_runtime.h>
#include <hip/hip_bf16.h>

// ---------------- constants ----------------
#define NB   4
#define DIM  128
#define KC   64
#define HH   48
#define WW   900
#define WPAD 1100
#define WST  1160   // guarded stride for conv-phase buffers: col = w + 2, zeros outside [0,1100)
#define NT   30
#define OC1  256
#define OC2  512
#define OC3  1024

typedef __attribute__((ext_vector_type(8))) short bf16x8;
typedef __attribute__((ext_vector_type(4))) float f32x4;
typedef unsigned short u16;
typedef unsigned int u32;

__device__ __forceinline__ u16 f2bf(float f){
  __hip_bfloat16 h = __float2bfloat16(f);
  u16 u; __builtin_memcpy(&u, &h, 2); return u;
}
__device__ __forceinline__ float bf2f(u16 u){
  __hip_bfloat16 h; __builtin_memcpy(&h, &u, 2); return __bfloat162float(h);
}

typedef __attribute__((address_space(1))) const u32 g_u32;
typedef __attribute__((address_space(3))) u32 l_u32;
// async global->LDS, 16B per lane; LDS dest = uniform base + lane*16
__device__ __forceinline__ void gll16(const void* g, void* l){
  __builtin_amdgcn_global_load_lds((g_u32*)g, (l_u32*)l, 16, 0, 0);
}

// ---------------- VLAD branch (fp32) ----------------

__global__ __launch_bounds__(256) void transpose_xt(const float* __restrict__ x, float* __restrict__ xt){
  __shared__ float tile[32][33];
  int n = blockIdx.z;
  int r0 = blockIdx.y*32, w0 = blockIdx.x*32;
  int t = threadIdx.x;
  int tr = t >> 5, tc = t & 31;
  #pragma unroll
  for (int i = 0; i < 4; ++i){
    int r = r0 + tr + i*8, w = w0 + tc;
    tile[tr + i*8][tc] = (w < WW) ? x[((size_t)n*(DIM*HH) + r)*WW + w] : 0.f;
  }
  __syncthreads();
  #pragma unroll
  for (int i = 0; i < 4; ++i){
    int w = w0 + tr + i*8, r = r0 + tc;
    if (w < WW) xt[((size_t)n*WW + w)*(DIM*HH) + r] = tile[tc][tr + i*8];
  }
}

__global__ __launch_bounds__(256) void vlad_softmax(const float* __restrict__ x,
    const float* __restrict__ conv_w, const float* __restrict__ conv_b, float* __restrict__ a){
  __shared__ float cwT[DIM*KC];
  __shared__ float cbs[KC];
  int t = threadIdx.x;
  for (int i = t; i < DIM*KC; i += 256){ int c = i >> 6, k = i & 63; cwT[i] = conv_w[k*DIM + c]; }
  if (t < KC) cbs[t] = conv_b[t];
  __syncthreads();
  int w = blockIdx.x*256 + t, h = blockIdx.y, n = blockIdx.z;
  bool ok = (w < WW);
  float lg[KC];
  #pragma unroll
  for (int k = 0; k < KC; ++k) lg[k] = cbs[k];
  const float* xp = x + (size_t)n*DIM*HH*WW + (size_t)h*WW + (ok ? w : 0);
  for (int c = 0; c < DIM; ++c){
    float xv = ok ? xp[(size_t)c*HH*WW] : 0.f;
    const float* cw = &cwT[c*KC];
    #pragma unroll
    for (int k = 0; k < KC; ++k) lg[k] += xv * cw[k];
  }
  float m = lg[0];
  #pragma unroll
  for (int k = 1; k < KC; ++k) m = fmaxf(m, lg[k]);
  float s = 0.f;
  #pragma unroll
  for (int k = 0; k < KC; ++k){ lg[k] = __expf(lg[k]-m); s += lg[k]; }
  float inv = 1.f/s;
  if (ok){
    float* dst = a + (((size_t)(n*HH + h))*WW + w)*KC;
    #pragma unroll
    for (int k = 0; k < KC; k += 4){
      float4 v = make_float4(lg[k]*inv, lg[k+1]*inv, lg[k+2]*inv, lg[k+3]*inv);
      *(float4*)&dst[k] = v;
    }
  }
}

__global__ __launch_bounds__(256) void vlad_xa(const float* __restrict__ xt, const float* __restrict__ a,
    float* __restrict__ xa, float* __restrict__ a_sum){
  __shared__ float aT[HH][KC];
  __shared__ float xT[DIM*HH];
  int t = threadIdx.x, w = blockIdx.x, n = blockIdx.y;
  for (int i = t; i < HH*KC; i += 256){
    int h = i >> 6, k = i & 63;
    aT[h][k] = a[(((size_t)(n*HH + h))*WW + w)*KC + k];
  }
  {
    const float4* src = (const float4*)(xt + ((size_t)n*WW + w)*(DIM*HH));
    float4* dst4 = (float4*)xT;
    for (int i = t; i < (DIM*HH)/4; i += 256) dst4[i] = src[i];
  }
  __syncthreads();
  int k = t >> 2, cb4 = t & 3;
  float areg[HH];
  #pragma unroll
  for (int h = 0; h < HH; ++h) areg[h] = aT[h][k];
  float* dst = xa + (((size_t)n*WW + w)*KC + k)*DIM;
  #pragma unroll 2
  for (int j = 0; j < 32; ++j){
    const float4* xr = (const float4*)&xT[(cb4 + 4*j)*HH];
    float s = 0.f;
    #pragma unroll
    for (int h4 = 0; h4 < HH/4; ++h4){
      float4 xv = xr[h4];
      s += areg[h4*4+0]*xv.x + areg[h4*4+1]*xv.y + areg[h4*4+2]*xv.z + areg[h4*4+3]*xv.w;
    }
    dst[cb4 + 4*j] = s;
  }
  if (t < KC){
    float s = 0.f;
    #pragma unroll
    for (int h = 0; h < HH; ++h) s += aT[h][t];
    a_sum[((size_t)n*WW + w)*KC + t] = s;
  }
}

__global__ __launch_bounds__(128) void vlad_win(const float* __restrict__ xa, const float* __restrict__ a_sum,
    const float* __restrict__ centers, float* __restrict__ vlad){
  int c = threadIdx.x, k = blockIdx.x, tt = blockIdx.y, n = blockIdx.z;
  float acc = 0.f, S = 0.f;
  for (int p = 0; p < 200; ++p){
    int w = (30*tt + p + 800) % 900;
    acc += xa[(((size_t)n*WW + w)*KC + k)*DIM + c];
    S   += a_sum[((size_t)n*WW + w)*KC + k];
  }
  float v = acc - centers[k*DIM + c]*S;
  float ss = v*v;
  #pragma unroll
  for (int m = 1; m < 64; m <<= 1) ss += __shfl_xor(ss, m);
  __shared__ float red[2];
  if ((c & 63) == 0) red[c >> 6] = ss;
  __syncthreads();
  float tot = red[0] + red[1];
  float inv = 1.f / fmaxf(sqrtf(tot), 1e-12f);
  vlad[(((size_t)(n*NT + tt))*KC + k)*DIM + c] = v*inv;
}

__global__ __launch_bounds__(256) void vlad_gnorm(float* __restrict__ vlad){
  int row = blockIdx.x, t = threadIdx.x;
  float4* v = (float4*)(vlad + (size_t)row*(KC*DIM));
  float4 r[8]; float ss = 0.f;
  #pragma unroll
  for (int i = 0; i < 8; ++i){
    r[i] = v[t + i*256];
    ss += r[i].x*r[i].x + r[i].y*r[i].y + r[i].z*r[i].z + r[i].w*r[i].w;
  }
  #pragma unroll
  for (int m = 1; m < 64; m <<= 1) ss += __shfl_xor(ss, m);
  __shared__ float red[4];
  if ((t & 63) == 0) red[t >> 6] = ss;
  __syncthreads();
  float tot = red[0]+red[1]+red[2]+red[3];
  float inv = 1.f / fmaxf(sqrtf(tot), 1e-12f);
  #pragma unroll
  for (int i = 0; i < 8; ++i){
    float4 o = r[i]; o.x*=inv; o.y*=inv; o.z*=inv; o.w*=inv;
    v[t + i*256] = o;
  }
}

// ---------------- conv tower (bf16 MFMA, NHWC, guarded stride WST) ----------------

// x [n][c][h][w] -> xpb [n][h][b=0..WST)[c], b = w+2, zeros outside valid circular range
__global__ __launch_bounds__(256) void build_xpb(const float* __restrict__ x, u16* __restrict__ xpb){
  __shared__ u16 tile[DIM][33];
  int t = threadIdx.x, h = blockIdx.y, n = blockIdx.z;
  int b0 = blockIdx.x*32;
  #pragma unroll
  for (int i = 0; i < 16; ++i){
    int e = t + i*256;
    int c = e >> 5, bl = e & 31;
    int b = b0 + bl, w = b - 2;
    float v = 0.f;
    if (w >= 0 && w < WPAD){
      int wsrc = (w + 800) % 900;
      v = x[((size_t)(n*DIM + c)*HH + h)*WW + wsrc];
    }
    tile[c][bl] = f2bf(v);
  }
  __syncthreads();
  #pragma unroll
  for (int i = 0; i < 16; ++i){
    int e = t + i*256;
    int bl = e >> 7, c = e & 127;
    int b = b0 + bl;
    if (b < WST) xpb[((size_t)(n*HH + h)*WST + b)*DIM + c] = tile[c][bl];
  }
}

// w OIHW fp32 -> wp [tap=dh*5+dw][oc][ic] bf16
__global__ __launch_bounds__(256) void pack_w(const float* __restrict__ w, u16* __restrict__ wp, int OC, int IC){
  int idx = blockIdx.x*256 + threadIdx.x;
  int total = OC*IC*25;
  if (idx >= total) return;
  int ic = idx % IC; int r = idx / IC; int oc = r % OC; int tap = r / OC;
  wp[idx] = f2bf(w[((size_t)oc*IC + ic)*25 + tap]);
}

// 5x5 conv pad 2, NHWC bf16, guarded input (alloc base = col0 = w=-2, stride WST).
// Block tile: 128oc x 128w; 4 waves each 64oc x 64w. global_load_lds staging with
// XOR chunk swizzle (chunk ^= row&7) applied on BOTH the global source and the read.
template<int IC, int OC, int H>
__global__ __launch_bounds__(256,2) void conv5x5(const u16* __restrict__ in, const u16* __restrict__ wp,
    const float* __restrict__ bias, u16* __restrict__ out){
  constexpr int NICB = IC/128;
  __shared__ u16 sIn[132*128];   // rows 0..131 = input w0-2 .. w0+129, 256B/row linear
  __shared__ u16 sW[128*128];    // rows = oc local
  int t = threadIdx.x;
  int wave = t >> 6, lane = t & 63, lr = lane & 15, lgp = lane >> 4;
  int w0  = blockIdx.x * 128;
  int ocb = blockIdx.y * 128;
  int nh = blockIdx.z; int n = nh / H, h = nh % H;
  int wo_oc = (wave & 1)*64, wo_w = (wave >> 1)*64;
  f32x4 acc[4][4] = {};
  const u16* inN = in + (size_t)n*H*WST*IC;   // col0 = w=-2
  for (int dh = 0; dh < 5; ++dh){
    int hin = h + dh - 2;
    if (hin < 0 || hin >= H) continue;
    const u16* rowbase = inN + (size_t)hin*WST*IC;
    for (int icb = 0; icb < NICB; ++icb){
      __syncthreads();  // prior reads of sIn/sW done before overwrite
      // stage sIn: 132 rows x 16 chunks = 2112 chunks = 33 gll instrs
      for (int i = wave; i < 33; i += 4){
        int qq = i*64 + lane;
        int r = qq >> 4, cp = qq & 15;
        int c = cp ^ (r & 7);
        gll16(rowbase + (size_t)(w0 + r)*IC + icb*128 + c*8, &sIn[i*512]);
      }
      for (int dw = 0; dw < 5; ++dw){
        if (dw) __syncthreads();  // waves done reading previous sW
        {
          int tap = dh*5 + dw;
          const u16* wsrc = wp + ((size_t)tap*OC + ocb)*IC + (size_t)icb*128;
          for (int i = wave; i < 32; i += 4){
            int qq = i*64 + lane;
            int r = qq >> 4, cp = qq & 15;
            int c = cp ^ (r & 7);
            gll16(wsrc + (size_t)r*IC + c*8, &sW[i*512]);
          }
        }
        __syncthreads();  // staging complete (vmcnt drained by barrier)
        #pragma unroll
        for (int k0i = 0; k0i < 4; ++k0i){
          bf16x8 A[4], B[4];
          #pragma unroll
          for (int j = 0; j < 4; ++j){
            int ar = wo_oc + j*16 + lr;
            A[j] = *(const bf16x8*)&sW[ar*128 + (((k0i*4 + lgp) ^ (lr & 7)) << 3)];
            int br = wo_w + j*16 + lr + dw;
            B[j] = *(const bf16x8*)&sIn[br*128 + (((k0i*4 + lgp) ^ (br & 7)) << 3)];
          }
          #pragma unroll
          for (int ja = 0; ja < 4; ++ja)
            #pragma unroll
            for (int jb = 0; jb < 4; ++jb)
              acc[ja][jb] = __builtin_amdgcn_mfma_f32_16x16x32_bf16(A[ja], B[jb], acc[ja][jb], 0, 0, 0);
        }
      }
    }
  }
  u16* outP = out + ((size_t)(n*H + h)*WST + 2)*OC;  // col = w+2
  #pragma unroll
  for (int ja = 0; ja < 4; ++ja){
    int oc = ocb + wo_oc + ja*16 + lgp*4;
    float4 bv = *(const float4*)&bias[oc];
    #pragma unroll
    for (int jb = 0; jb < 4; ++jb){
      int wg = w0 + wo_w + jb*16 + lr;
      if (wg < WPAD){
        f32x4 av = acc[ja][jb];
        ushort4 o;
        o.x = f2bf(av[0] + bv.x);
        o.y = f2bf(av[1] + bv.y);
        o.z = f2bf(av[2] + bv.z);
        o.w = f2bf(av[3] + bv.w);
        *(ushort4*)(outP + (size_t)wg*OC + oc) = o;
      }
    }
  }
}

// leaky(0.2) + maxpool 3x3 stride(3,1) wpad 1; writes full guarded range (zeros outside)
__global__ __launch_bounds__(256) void pool1k(const u16* __restrict__ in, u16* __restrict__ out){
  int oc = threadIdx.x, wb = blockIdx.x, ho = blockIdx.y, n = blockIdx.z;
  int wo = wb - 2;
  float m = 0.f;
  if (wo >= 0 && wo < WPAD){
    m = -1e30f;
    #pragma unroll
    for (int kh = 0; kh < 3; ++kh){
      const u16* row = in + ((size_t)(n*HH + ho*3 + kh)*WST + 2)*OC1;
      #pragma unroll
      for (int kw = 0; kw < 3; ++kw){
        int wi = wo - 1 + kw;
        if (wi >= 0 && wi < WPAD) m = fmaxf(m, bf2f(row[(size_t)wi*OC1 + oc]));
      }
    }
    m = (m > 0.f) ? m : 0.2f*m;
  }
  out[((size_t)(n*16 + ho)*WST + wb)*OC1 + oc] = f2bf(m);
}

// leaky(0.2) + maxpool 4x5 stride(4,1) wpad 2
__global__ __launch_bounds__(256) void pool2k(const u16* __restrict__ in, u16* __restrict__ out){
  int wb = blockIdx.x, ho = blockIdx.y, n = blockIdx.z;
  int wo = wb - 2;
  #pragma unroll
  for (int j = 0; j < 2; ++j){
    int oc = threadIdx.x + j*256;
    float m = 0.f;
    if (wo >= 0 && wo < WPAD){
      m = -1e30f;
      #pragma unroll
      for (int kh = 0; kh < 4; ++kh){
        const u16* row = in + ((size_t)(n*16 + ho*4 + kh)*WST + 2)*OC2;
        #pragma unroll
        for (int kw = 0; kw < 5; ++kw){
          int wi = wo - 2 + kw;
          if (wi >= 0 && wi < WPAD) m = fmaxf(m, bf2f(row[(size_t)wi*OC2 + oc]));
        }
      }
      m = (m > 0.f) ? m : 0.2f*m;
    }
    out[((size_t)(n*4 + ho)*WST + wb)*OC2 + oc] = f2bf(m);
  }
}

// maxpool 4x200, sample every 30 -> xfraw [n][t][1024] fp32
__global__ __launch_bounds__(256) void pool3k(const u16* __restrict__ in, float* __restrict__ xfraw){
  int tt = blockIdx.x, ocg = blockIdx.y, n = blockIdx.z;
  int oc = ocg*256 + threadIdx.x;
  float m = -1e30f;
  for (int hh = 0; hh < 4; ++hh){
    const u16* row = in + ((size_t)(n*4 + hh)*WST + 2 + 30*tt)*OC3 + oc;
    for (int p = 0; p < 200; ++p) m = fmaxf(m, bf2f(row[(size_t)p*OC3]));
  }
  xfraw[(size_t)(n*NT + tt)*OC3 + oc] = m;
}

__global__ __launch_bounds__(256) void xf_norm(const float* __restrict__ xfraw, float* __restrict__ xf){
  int row = blockIdx.x, t = threadIdx.x;
  const float* src = xfraw + (size_t)row*OC3;
  float v[4]; float ss = 0.f;
  #pragma unroll
  for (int j = 0; j < 4; ++j){ v[j] = src[t + j*256]; ss += v[j]*v[j]; }
  #pragma unroll
  for (int m = 1; m < 64; m <<= 1) ss += __shfl_xor(ss, m);
  __shared__ float red[4];
  if ((t & 63) == 0) red[t >> 6] = ss;
  __syncthreads();
  float tot = red[0]+red[1]+red[2]+red[3];
  float inv = 1.f/fmaxf(sqrtf(tot), 1e-12f);
  float* dst = xf + (size_t)row*OC3;
  #pragma unroll
  for (int j = 0; j < 4; ++j) dst[t + j*256] = v[j]*inv;
}

__global__ __launch_bounds__(256) void final_mlp(const float* __restrict__ vlad, const float* __restrict__ xf,
    const float* __restrict__ W, const float* __restrict__ b, float* __restrict__ out){
  __shared__ float feat[9216];
  __shared__ float red[4];
  int row = blockIdx.x, t = threadIdx.x;
  {
    const float4* v = (const float4*)(vlad + (size_t)row*8192);
    float4* f4 = (float4*)feat;
    for (int i = t; i < 2048; i += 256) f4[i] = v[i];
    const float4* xv = (const float4*)(xf + (size_t)row*1024);
    if (t < 256) f4[2048 + t] = xv[t];
  }
  __syncthreads();
  const float* wr = W + (size_t)t*9216;
  float acc = b[t];
  for (int i = 0; i < 9216; i += 4){
    float4 wv = *(const float4*)&wr[i];
    acc += feat[i]*wv.x + feat[i+1]*wv.y + feat[i+2]*wv.z + feat[i+3]*wv.w;
  }
  float ss = acc*acc;
  #pragma unroll
  for (int m = 1; m < 64; m <<= 1) ss += __shfl_xor(ss, m);
  if ((t & 63) == 0) red[t >> 6] = ss;
  __syncthreads();
  float tot = red[0]+red[1]+red[2]+red[3];
  float inv = 1.f/fmaxf(sqrtf(tot), 1e-12f);
  out[(size_t)row*256 + t] = acc*inv;
}

// ---------------- launch ----------------
extern "C" void kernel_launch(void* const* d_in, const int* in_sizes, int n_in,
                              void* d_out, int out_size, void* d_ws, size_t ws_size,
                              hipStream_t stream){
  const float* x       = (const float*)d_in[0];
  const float* centers = (const float*)d_in[1];
  const float* conv_w  = (const float*)d_in[2];
  const float* conv_b  = (const float*)d_in[3];
  const float* w1      = (const float*)d_in[4];
  const float* b1      = (const float*)d_in[5];
  const float* w2      = (const float*)d_in[6];
  const float* b2      = (const float*)d_in[7];
  const float* w3      = (const float*)d_in[8];
  const float* b3      = (const float*)d_in[9];
  const float* mlp_w   = (const float*)d_in[10];
  const float* mlp_b   = (const float*)d_in[11];
  float* out = (float*)d_out;
  char* ws = (char*)d_ws;
  const size_t MB = 1ull << 20;
  if (ws_size < 248*MB) return;

  // persistent small buffers
  float* vlad  = (float*)(ws + 0);        // 3.75 MiB
  float* xf    = (float*)(ws + 4*MB);     // 0.47 MiB
  float* asum  = (float*)(ws + 5*MB);     // 0.88 MiB
  float* xfraw = (float*)(ws + 6*MB);     // 0.47 MiB
  char*  AR    = ws + 7*MB;               // arena (241 MiB), phase-reused
  // VLAD phase
  float* xt = (float*)(AR + 0);           // 84.4 MiB
  float* a  = (float*)(AR + 85*MB);       // 42.2 MiB
  float* xa = (float*)(AR + 128*MB);      // 112.5 MiB
  // conv phase (after vlad_win; regions recycled)
  u16* xpb = (u16*)(AR + 0);              // 54.4 MiB (over xt)
  u16* wp1 = (u16*)(AR + 55*MB);          // 1.6 MiB
  u16* wp2 = (u16*)(AR + 57*MB);          // 6.25 MiB
  u16* wp3 = (u16*)(AR + 64*MB);          // 25 MiB
  u16* h1  = (u16*)(AR + 89*MB);          // 108.75 MiB (over a/xa)
  u16* p1  = (u16*)(AR + 0);              // 36.25 MiB (over xpb, dead after conv1)
  u16* h2  = (u16*)(AR + 89*MB);          // 72.5 MiB (over h1, dead after pool1)
  u16* p2  = (u16*)(AR + 163*MB);         // 18.1 MiB (past h2)
  u16* h3  = (u16*)(AR + 0);              // 36.25 MiB (over p1, dead after conv2)

  // ---- VLAD (fp32) ----
  transpose_xt<<<dim3(29,192,NB), 256, 0, stream>>>(x, xt);
  vlad_softmax<<<dim3(4,HH,NB), 256, 0, stream>>>(x, conv_w, conv_b, a);
  vlad_xa<<<dim3(WW,NB), 256, 0, stream>>>(xt, a, xa, asum);
  vlad_win<<<dim3(KC,NT,NB), 128, 0, stream>>>(xa, asum, centers, vlad);
  vlad_gnorm<<<dim3(NB*NT), 256, 0, stream>>>(vlad);

  // ---- conv tower (bf16 MFMA) ----
  pack_w<<<dim3(3200),  256, 0, stream>>>(w1, wp1, OC1, DIM);
  pack_w<<<dim3(12800), 256, 0, stream>>>(w2, wp2, OC2, OC1);
  pack_w<<<dim3(51200), 256, 0, stream>>>(w3, wp3, OC3, OC2);
  build_xpb<<<dim3(37,HH,NB), 256, 0, stream>>>(x, xpb);
  conv5x5<128,256,48><<<dim3(9, OC1/128, NB*HH), 256, 0, stream>>>(xpb, wp1, b1, h1);
  pool1k<<<dim3(WST,16,NB), 256, 0, stream>>>(h1, p1);
  conv5x5<256,512,16><<<dim3(9, OC2/128, NB*16), 256, 0, stream>>>(p1, wp2, b2, h2);
  pool2k<<<dim3(WST,4,NB), 256, 0, stream>>>(h2, p2);
  conv5x5<512,1024,4><<<dim3(9, OC3/128, NB*4), 256, 0, stream>>>(p2, wp3, b3, h3);
  pool3k<<<dim3(NT,4,NB), 256, 0, stream>>>(h3, xfraw);
  xf_norm<<<dim3(NB*NT), 256, 0, stream>>>(xfraw, xf);

  // ---- head ----
  final_mlp<<<dim3(NB*NT), 256, 0, stream>>>(vlad, xf, mlp_w, mlp_b, out);
}